// Round 3
// baseline (760.883 us; speedup 1.0000x reference)
//
#include <hip/hip_runtime.h>

typedef short short8 __attribute__((ext_vector_type(8)));
typedef float f32x4 __attribute__((ext_vector_type(4)));
typedef unsigned short ushort_t;

#define VOCAB 30000
#define DW 512
#define KDIM 512
#define HDIM 512
#define G3 1536
#define TT 50
#define BB 128
#define M_ROWS 6400   /* T*B */
#define NPAD 30208    /* 118*256 */
#define NT2 472       /* partial tiles: 118 nblocks x 4 wc-waves */

__device__ __forceinline__ float b2f(ushort_t u){ return __uint_as_float(((unsigned)u)<<16); }
__device__ __forceinline__ ushort_t f2b(float f){
    unsigned u = __float_as_uint(f);
    unsigned r = (u + 0x7fffu + ((u>>16)&1u)) >> 16;
    return (ushort_t)r;
}
__device__ __forceinline__ float sigf(float x){
    float e = __expf(-x);
    return __builtin_amdgcn_rcpf(1.0f + e);
}
__device__ __forceinline__ float tanh_(float x){
    return 2.0f*sigf(2.0f*x) - 1.0f;   // safe at +-inf
}
__device__ __forceinline__ void gload16(const ushort_t* g, char* l){
    __builtin_amdgcn_global_load_lds((const __attribute__((address_space(1))) void*)g,
                                     (__attribute__((address_space(3))) void*)l, 16, 0, 0);
}

// ---------- setup kernels ----------
__global__ void k_cvt(const float* __restrict__ s, ushort_t* __restrict__ d, int n){
    int i = blockIdx.x*blockDim.x + threadIdx.x;
    if (i < n) d[i] = f2b(s[i]);
}
__global__ void k_zero_u(ushort_t* __restrict__ d, int n){
    int i = blockIdx.x*blockDim.x + threadIdx.x;
    if (i < n) d[i] = 0;
}
__global__ void k_gather(const float* __restrict__ emb, const int* __restrict__ idx,
                         ushort_t* __restrict__ x){
    int row = blockIdx.x;
    int v = idx[row];
    const float* src = emb + (size_t)v*DW;
    ushort_t* dst = x + (size_t)row*DW;
    for (int d = threadIdx.x; d < DW; d += blockDim.x) dst[d] = f2b(src[d]);
}
__global__ void k_biasg(const float* __restrict__ bi, const float* __restrict__ bh,
                        float* __restrict__ bg){
    int i = blockIdx.x*blockDim.x + threadIdx.x;
    if (i < G3) bg[i] = bi[i] + (i < 2*HDIM ? bh[i] : 0.0f);
}
__global__ void k_zero_h(float* __restrict__ hf, ushort_t* __restrict__ hb, int n){
    int i = blockIdx.x*blockDim.x + threadIdx.x;
    if (i < n){ hf[i] = 0.0f; hb[i] = 0; }
}

// ---------- 256x256 pipelined bf16 GEMM: C = A[Mx512] * B[Nx512]^T ----------
// 512 thr = 8 waves (2M x 4N), per-wave C = 128x64 (8x4 frags), BK=64, NTILES=8.
// Depth-2 double-buffer, counted vmcnt, raw barriers, T2 both-sides XOR swizzle.
// MODE 0: bf16 C + bias, row stride G3.  MODE 1: per-row (max,sumexp) partials.
template<int MODE, int NBLK>
__global__ __launch_bounds__(512, 2) void k_gemm2(const ushort_t* __restrict__ A,
        const ushort_t* __restrict__ Bw, const float* __restrict__ bias,
        ushort_t* __restrict__ Cout, float* __restrict__ pmax, float* __restrict__ psum){
    __shared__ ushort_t lds[2][2][256*64];   // [buf][A/B][row*64+col] = 128 KiB
    const int nwg = NBLK * (M_ROWS/256);
    // T1: bijective XCD swizzle (m204)
    int orig = blockIdx.x;
    int q = nwg >> 3, r = nwg & 7;
    int xcd = orig & 7, seq = orig >> 3;
    int wgid = (xcd < r ? xcd*(q+1) : r*(q+1) + (xcd-r)*q) + seq;
    int nb = wgid % NBLK, mb = wgid / NBLK;
    int n0 = nb*256, m0 = mb*256;

    int tid = threadIdx.x;
    int lane = tid & 63, wv = tid >> 6;
    int lo = lane & 15, hi = lane >> 4;
    int wr = wv >> 2, wc = wv & 3;

    // staging role: waves 0-3 stage A rows [wv*64,+64), waves 4-7 stage B rows [(wv-4)*64,+64)
    int smat = (wv < 4) ? 0 : 1;
    int srow = (wv & 3) * 64;
    int lrow = lane >> 3, lslot = lane & 7;           // 8 rows x 8 slots per 1KB call
    int xsl  = lslot ^ (lrow & 7);                    // T2 source pre-swizzle
    const ushort_t* gsrc = (smat == 0 ? A + (size_t)m0*KDIM : Bw + (size_t)n0*KDIM)
                           + (size_t)(srow + lrow)*KDIM + xsl*8;
    ushort_t* lbase = &lds[0][0][0];

    #define STAGE(kt, bs) do {                                                   \
        const ushort_t* _g = gsrc + (kt)*64;                                     \
        ushort_t* _l = &lds[bs][smat][srow*64];                                  \
        _Pragma("unroll")                                                        \
        for (int _c = 0; _c < 8; ++_c)                                           \
            gload16(_g + (size_t)_c*8*KDIM, (char*)(_l + _c*8*64));              \
    } while(0)

    int xr2 = lo & 7;   // (frag_row & 7) for all fragment reads
    #define RD_A(bs, mf, ks) (*(const short8*)&lds[bs][0][(wr*128 + (mf)*16 + lo)*64 + ((((ks)*4+hi)^xr2)*8)])
    #define RD_B(bs, nf, ks) (*(const short8*)&lds[bs][1][(wc*64  + (nf)*16 + lo)*64 + ((((ks)*4+hi)^xr2)*8)])

    f32x4 acc[8][4] = {};
    STAGE(0, 0);
    STAGE(1, 1);
    short8 av[8], bv[4], av2[8], bv2[4];
    #pragma unroll
    for (int t = 0; t < 8; ++t){
        const int bs = t & 1;
        if (t < 7) asm volatile("s_waitcnt vmcnt(8)" ::: "memory");
        else       asm volatile("s_waitcnt vmcnt(0)" ::: "memory");
        __builtin_amdgcn_s_barrier();                 // tile t resident; prev reads done
        asm volatile("" ::: "memory");
        #pragma unroll
        for (int mf = 0; mf < 8; ++mf) av[mf] = RD_A(bs, mf, 0);
        #pragma unroll
        for (int nf = 0; nf < 4; ++nf) bv[nf] = RD_B(bs, nf, 0);
        __builtin_amdgcn_s_setprio(1);
        #pragma unroll
        for (int mf = 0; mf < 8; ++mf)
            #pragma unroll
            for (int nf = 0; nf < 4; ++nf)
                acc[mf][nf] = __builtin_amdgcn_mfma_f32_16x16x32_bf16(av[mf], bv[nf], acc[mf][nf], 0, 0, 0);
        __builtin_amdgcn_s_setprio(0);
        #pragma unroll
        for (int mf = 0; mf < 8; ++mf) av2[mf] = RD_A(bs, mf, 1);
        #pragma unroll
        for (int nf = 0; nf < 4; ++nf) bv2[nf] = RD_B(bs, nf, 1);
        asm volatile("s_waitcnt lgkmcnt(0)" ::: "memory");
        __builtin_amdgcn_sched_barrier(0);
        __builtin_amdgcn_s_barrier();                 // all waves done reading buf[bs]
        asm volatile("" ::: "memory");
        if (t + 2 < 8) STAGE(t + 2, bs);              // overwrite just-freed buffer
        __builtin_amdgcn_s_setprio(1);
        #pragma unroll
        for (int mf = 0; mf < 8; ++mf)
            #pragma unroll
            for (int nf = 0; nf < 4; ++nf)
                acc[mf][nf] = __builtin_amdgcn_mfma_f32_16x16x32_bf16(av2[mf], bv2[nf], acc[mf][nf], 0, 0, 0);
        __builtin_amdgcn_s_setprio(0);
    }
    #undef STAGE
    #undef RD_A
    #undef RD_B
    (void)lbase;

    if (MODE == 0){
        #pragma unroll
        for (int nf = 0; nf < 4; ++nf){
            int n = n0 + wc*64 + nf*16 + lo;
            float bb = bias[n];
            #pragma unroll
            for (int mf = 0; mf < 8; ++mf){
                #pragma unroll
                for (int j = 0; j < 4; ++j){
                    int m = m0 + wr*128 + mf*16 + hi*4 + j;
                    Cout[(size_t)m*G3 + n] = f2b(acc[mf][nf][j] + bb);
                }
            }
        }
    } else {
        float bov[4];
        bool valid[4];
        #pragma unroll
        for (int nf = 0; nf < 4; ++nf){
            int col = n0 + wc*64 + nf*16 + lo;
            valid[nf] = (col < VOCAB);
            bov[nf] = valid[nf] ? bias[col] : 0.0f;
        }
        int tile = nb*4 + wc;
        #pragma unroll
        for (int mf = 0; mf < 8; ++mf){
            #pragma unroll
            for (int j = 0; j < 4; ++j){
                float lv[4];
                #pragma unroll
                for (int nf = 0; nf < 4; ++nf)
                    lv[nf] = valid[nf] ? (acc[mf][nf][j] + bov[nf]) : -1e30f;
                float mx = fmaxf(fmaxf(lv[0], lv[1]), fmaxf(lv[2], lv[3]));
                for (int d = 1; d < 16; d <<= 1) mx = fmaxf(mx, __shfl_xor(mx, d, 64));
                float s = 0.0f;
                #pragma unroll
                for (int nf = 0; nf < 4; ++nf)
                    s += __expf(lv[nf] - mx);
                for (int d = 1; d < 16; d <<= 1) s += __shfl_xor(s, d, 64);
                if (lo == 0){
                    int m = m0 + wr*128 + mf*16 + hi*4 + j;
                    pmax[(size_t)tile*M_ROWS + m] = mx;
                    psum[(size_t)tile*M_ROWS + m] = s;
                }
            }
        }
    }
}

// ---------- one GRU step: grid (32 ctiles, 8 btiles), block 192 (3 waves = 3 gates) ----------
__global__ __launch_bounds__(192) void k_step(const ushort_t* __restrict__ hprev_b,
        const float* __restrict__ hprev_f, const ushort_t* __restrict__ Whh,
        const ushort_t* __restrict__ xg, const float* __restrict__ bh,
        float* __restrict__ hnext_f, ushort_t* __restrict__ hnext_b,
        ushort_t* __restrict__ outs, int t){
    __shared__ float sg[3][16][16];
    int lane = threadIdx.x & 63, g = threadIdx.x >> 6;
    int lo = lane & 15, hi = lane >> 4;
    int c16 = blockIdx.x * 16, b0 = blockIdx.y * 16;
    f32x4 acc = {};
    const ushort_t* Arow = hprev_b + (size_t)(b0 + lo)*HDIM;
    const ushort_t* Brow = Whh + (size_t)(g*HDIM + c16 + lo)*HDIM;
    #pragma unroll
    for (int kk = 0; kk < 16; ++kk){
        int k0 = kk*32 + hi*8;
        short8 a = *(const short8*)(Arow + k0);
        short8 b = *(const short8*)(Brow + k0);
        acc = __builtin_amdgcn_mfma_f32_16x16x32_bf16(a, b, acc, 0, 0, 0);
    }
    #pragma unroll
    for (int j = 0; j < 4; ++j) sg[g][hi*4+j][lo] = acc[j];
    __syncthreads();
    if (g == 0){
        int c = c16 + lo;
        float bhn = bh[2*HDIM + c];
        const ushort_t* xgt = xg + (size_t)t*BB*G3;
        #pragma unroll
        for (int j = 0; j < 4; ++j){
            int bt = b0 + hi*4 + j;
            float xr = b2f(xgt[(size_t)bt*G3 + c]);
            float xz = b2f(xgt[(size_t)bt*G3 + HDIM + c]);
            float xn = b2f(xgt[(size_t)bt*G3 + 2*HDIM + c]);
            float r  = sigf(sg[0][hi*4+j][lo] + xr);
            float z  = sigf(sg[1][hi*4+j][lo] + xz);
            float n  = tanh_(xn + r*(sg[2][hi*4+j][lo] + bhn));
            float hold = hprev_f[(size_t)bt*HDIM + c];
            float hnew = (1.0f - z)*n + z*hold;
            hnext_f[(size_t)bt*HDIM + c] = hnew;
            ushort_t hb = f2b(hnew);
            hnext_b[(size_t)bt*HDIM + c] = hb;
            outs[((size_t)t*BB + bt)*HDIM + c] = hb;
        }
    }
}

// ---------- combine partials -> lse ----------
__global__ void k_comb(const float* __restrict__ pmax, const float* __restrict__ psum,
                       float* __restrict__ lse){
    int r = blockIdx.x*blockDim.x + threadIdx.x;
    if (r >= M_ROWS) return;
    float M = -1e30f;
    for (int t = 0; t < NT2; ++t) M = fmaxf(M, pmax[(size_t)t*M_ROWS + r]);
    float S = 0.0f;
    for (int t = 0; t < NT2; ++t) S += psum[(size_t)t*M_ROWS + r] * __expf(pmax[(size_t)t*M_ROWS + r] - M);
    lse[r] = M + __logf(S);
}

// ---------- nll per row ----------
__global__ __launch_bounds__(256) void k_loss(const ushort_t* __restrict__ outs,
        const ushort_t* __restrict__ Wo, const float* __restrict__ bo,
        const float* __restrict__ lse, const int* __restrict__ tgt,
        float* __restrict__ out){
    int lane = threadIdx.x & 63, wv = threadIdx.x >> 6;
    int row = blockIdx.x*4 + wv;
    int tg = tgt[row];
    const ushort_t* a = outs + (size_t)row*HDIM + lane*8;
    const ushort_t* w = Wo + (size_t)tg*DW + lane*8;
    float s = 0.0f;
    #pragma unroll
    for (int j = 0; j < 8; ++j) s += b2f(a[j]) * b2f(w[j]);
    for (int d = 1; d < 64; d <<= 1) s += __shfl_xor(s, d, 64);
    if (lane == 0){
        float logit = s + bo[tg];
        out[row] = (tg != 0) ? (lse[row] - logit) : 0.0f;
    }
}

// ---------- obj = sum(loss)/max(count,1) ----------
__global__ __launch_bounds__(1024) void k_obj(const float* __restrict__ loss,
        const int* __restrict__ tgt, float* __restrict__ out){
    __shared__ float ss[1024];
    __shared__ int   sc[1024];
    float s = 0.0f; int c = 0;
    for (int i = threadIdx.x; i < M_ROWS; i += 1024){
        s += loss[i];
        c += (tgt[i] != 0) ? 1 : 0;
    }
    ss[threadIdx.x] = s; sc[threadIdx.x] = c;
    __syncthreads();
    for (int d = 512; d > 0; d >>= 1){
        if (threadIdx.x < (unsigned)d){ ss[threadIdx.x] += ss[threadIdx.x+d]; sc[threadIdx.x] += sc[threadIdx.x+d]; }
        __syncthreads();
    }
    if (threadIdx.x == 0) out[M_ROWS] = ss[0] / (float)(sc[0] > 0 ? sc[0] : 1);
}

extern "C" void kernel_launch(void* const* d_in, const int* in_sizes, int n_in,
                              void* d_out, int out_size, void* d_ws, size_t ws_size,
                              hipStream_t stream) {
    const int*   review_input  = (const int*)d_in[2];
    const int*   review_target = (const int*)d_in[3];
    const float* word_emb = (const float*)d_in[4];
    const float* W_ih = (const float*)d_in[5];
    const float* W_hh = (const float*)d_in[6];
    const float* b_ih = (const float*)d_in[7];
    const float* b_hh = (const float*)d_in[8];
    const float* W_out = (const float*)d_in[9];
    const float* b_out = (const float*)d_in[10];
    float* out = (float*)d_out;
    (void)n_in; (void)in_sizes; (void)out_size; (void)ws_size;

    char* ws = (char*)d_ws;
    size_t off = 0;
    auto alloc = [&](size_t bytes)->char*{
        char* p = ws + off;
        off = (off + bytes + 255) & ~(size_t)255;
        return p;
    };
    ushort_t* Wout_b = (ushort_t*)alloc((size_t)NPAD*DW*2);      // 30.9 MB (padded)
    ushort_t* Wih_b  = (ushort_t*)alloc((size_t)G3*DW*2);
    ushort_t* Whh_b  = (ushort_t*)alloc((size_t)G3*HDIM*2);
    ushort_t* outs_b = (ushort_t*)alloc((size_t)M_ROWS*HDIM*2);  // live through phase C
    float*    biasg  = (float*)alloc((size_t)G3*4);
    float*    h_f    = (float*)alloc((size_t)2*BB*HDIM*4);
    ushort_t* h_b    = (ushort_t*)alloc((size_t)2*BB*HDIM*2);
    float*    lse    = (float*)alloc((size_t)M_ROWS*4);
    // xb + xg dead by phase C -> pmax/psum alias this span
    ushort_t* xb     = (ushort_t*)alloc((size_t)M_ROWS*DW*2);
    ushort_t* xg     = (ushort_t*)alloc((size_t)M_ROWS*G3*2);
    float*    pmax   = (float*)xb;
    float*    psum   = pmax + (size_t)NT2*M_ROWS;

    k_cvt<<<(G3*DW+255)/256, 256, 0, stream>>>(W_ih, Wih_b, G3*DW);
    k_cvt<<<(G3*HDIM+255)/256, 256, 0, stream>>>(W_hh, Whh_b, G3*HDIM);
    k_cvt<<<(VOCAB*DW+255)/256, 256, 0, stream>>>(W_out, Wout_b, VOCAB*DW);
    k_zero_u<<<((NPAD-VOCAB)*DW+255)/256, 256, 0, stream>>>(Wout_b + (size_t)VOCAB*DW, (NPAD-VOCAB)*DW);
    k_gather<<<M_ROWS, 256, 0, stream>>>(word_emb, review_input, xb);
    k_biasg<<<(G3+255)/256, 256, 0, stream>>>(b_ih, b_hh, biasg);
    k_zero_h<<<(BB*HDIM+255)/256, 256, 0, stream>>>(h_f, h_b, BB*HDIM);

    // phase A: xg = x @ W_ih^T + biasg   (6 n-blocks x 25 m-blocks)
    k_gemm2<0, 6><<<6*(M_ROWS/256), 512, 0, stream>>>(xb, Wih_b, biasg, xg, nullptr, nullptr);

    // phase B: 50 sequential steps, double-buffered h
    for (int t = 0; t < TT; ++t){
        int cur = t & 1, nxt = cur ^ 1;
        k_step<<<dim3(HDIM/16, BB/16), 192, 0, stream>>>(h_b + (size_t)cur*BB*HDIM,
                                       h_f + (size_t)cur*BB*HDIM,
                                       Whh_b, xg, b_hh,
                                       h_f + (size_t)nxt*BB*HDIM,
                                       h_b + (size_t)nxt*BB*HDIM,
                                       outs_b, t);
    }

    // phase C: fused logits + LSE partials (118 n-blocks x 25 m-blocks), combine, nll, obj
    k_gemm2<1, 118><<<118*(M_ROWS/256), 512, 0, stream>>>(outs_b, Wout_b, b_out, nullptr, pmax, psum);
    k_comb<<<(M_ROWS+255)/256, 256, 0, stream>>>(pmax, psum, lse);
    k_loss<<<M_ROWS/4, 256, 0, stream>>>(outs_b, Wout_b, b_out, lse, review_target, out);
    k_obj<<<1, 1024, 0, stream>>>(out, review_target, out);
}